// Round 1
// baseline (76.941 us; speedup 1.0000x reference)
//
#include <hip/hip_runtime.h>
#include <math.h>

#define WIN 1024
#define NH 64

// One block (256 threads = 4 waves) per frame.
// Stage y[n] = normalizer * gauss[n] * x[n] in LDS (k-independent), then each
// wave computes 16 of the 64 harmonic DTFT magnitudes via fract+v_sin/v_cos
// (hardware sin/cos take REVOLUTIONS — phase is exactly fc*n revolutions).
__global__ __launch_bounds__(256) void morlet_kernel(
    const float* __restrict__ x,    // [F, 1024]
    const float* __restrict__ f0,   // [F]
    float* __restrict__ hd,         // [F, 64]
    float* __restrict__ amp)        // [F]
{
    const int frame = blockIdx.x;
    const int tid   = threadIdx.x;
    const int lane  = tid & 63;
    const int wave  = tid >> 6;

    __shared__ float y[WIN];
    __shared__ float tk[NH];

    // ---- stage windowed frame into LDS (float4 per thread) ----
    {
        const float4 xv =
            reinterpret_cast<const float4*>(x + (size_t)frame * WIN)[tid];
        const float inv_tp = 1.0f / 16000.0f;          // 1/tp
        const float norm   = 0.0044603129f;            // 1/sqrt(pi*16000)
        const int n0 = tid * 4;
        const float d0 = (float)(n0 - 512);
        const float d1 = d0 + 1.0f;
        const float d2 = d0 + 2.0f;
        const float d3 = d0 + 3.0f;
        y[n0 + 0] = xv.x * (norm * __expf(-d0 * d0 * inv_tp));
        y[n0 + 1] = xv.y * (norm * __expf(-d1 * d1 * inv_tp));
        y[n0 + 2] = xv.z * (norm * __expf(-d2 * d2 * inv_tp));
        y[n0 + 3] = xv.w * (norm * __expf(-d3 * d3 * inv_tp));
    }
    __syncthreads();

    const float f0v = f0[frame];

    // ---- 64 harmonics, 16 per wave ----
    for (int kk = wave; kk < NH; kk += 4) {
        const float kf = (float)(kk + 1);
        const float fc = f0v * kf * (1.0f / 16000.0f); // normalized freq (revolutions/sample)
        float re = 0.0f, im = 0.0f;
        if (fc <= 0.5f) {
            #pragma unroll
            for (int j = 0; j < WIN / 64; ++j) {
                const int n = lane + 64 * j;
                float t = fc * (float)n;               // phase in revolutions
                t -= floorf(t);                        // range-reduce to [0,1)
                const float s  = __builtin_amdgcn_sinf(t);  // sin(2*pi*t)
                const float c  = __builtin_amdgcn_cosf(t);  // cos(2*pi*t)
                const float yv = y[n];                 // 2 lanes/bank -> conflict-free
                re = fmaf(yv, c, re);
                im = fmaf(yv, -s, im);                 // e^{-2pi i t} = c - i s
            }
            // 64-lane butterfly reduction
            #pragma unroll
            for (int off = 32; off > 0; off >>= 1) {
                re += __shfl_xor(re, off, 64);
                im += __shfl_xor(im, off, 64);
            }
        }
        if (lane == 0) tk[kk] = sqrtf(re * re + im * im);
    }
    __syncthreads();

    // ---- normalize across k, write outputs (wave 0 only) ----
    if (tid < NH) {
        const float v = tk[tid];
        float s = v;
        #pragma unroll
        for (int off = 32; off > 0; off >>= 1)
            s += __shfl_xor(s, off, 64);
        hd[(size_t)frame * NH + tid] = v / s;
        if (tid == 0)
            amp[frame] = fminf(fmaxf(s * 2.0f, 0.0f), 1.0f);
    }
}

extern "C" void kernel_launch(void* const* d_in, const int* in_sizes, int n_in,
                              void* d_out, int out_size, void* d_ws, size_t ws_size,
                              hipStream_t stream) {
    const float* x   = (const float*)d_in[0];   // audio_frames [B,T,C,1024] f32
    const float* f0  = (const float*)d_in[1];   // f0 [B,T,C] f32
    const int F = in_sizes[1];                  // B*T*C frames (800)
    float* hd  = (float*)d_out;                 // [F,64]
    float* amp = (float*)d_out + (size_t)F * NH; // [F]
    morlet_kernel<<<F, 256, 0, stream>>>(x, f0, hd, amp);
}

// Round 2
// 70.127 us; speedup vs baseline: 1.0972x; 1.0972x over previous
//
#include <hip/hip_runtime.h>
#include <math.h>

#define WIN 1024
#define NH 64

// One block (256 threads = 4 waves) per frame.
// y[n] = norm*gauss[n]*x[n] staged in LDS once (k-independent), then each wave
// computes 16 contiguous harmonics in 4 batches of 4 via phasor recurrence:
// e^{-2pi i fc (n+64)} = e^{-2pi i fc n} * e^{-2pi i fc 64}; sin/cos only at
// batch setup (hardware v_sin/v_cos take REVOLUTIONS = exactly fc*n).
__global__ __launch_bounds__(256) void morlet_kernel(
    const float* __restrict__ x,    // [F, 1024]
    const float* __restrict__ f0,   // [F]
    float* __restrict__ hd,         // [F, 64]
    float* __restrict__ amp)        // [F]
{
    const int frame = blockIdx.x;
    const int tid   = threadIdx.x;
    const int lane  = tid & 63;
    const int wave  = tid >> 6;

    __shared__ float ysh[WIN];
    __shared__ float tk[NH];

    // ---- stage windowed frame into LDS (float4 per thread) ----
    {
        const float4 xv =
            reinterpret_cast<const float4*>(x + (size_t)frame * WIN)[tid];
        const float inv_tp = 1.0f / 16000.0f;          // 1/tp
        const float norm   = 0.0044603129f;            // 1/sqrt(pi*16000)
        const int n0 = tid * 4;
        const float d0 = (float)(n0 - 512);
        const float d1 = d0 + 1.0f;
        const float d2 = d0 + 2.0f;
        const float d3 = d0 + 3.0f;
        ysh[n0 + 0] = xv.x * (norm * __expf(-d0 * d0 * inv_tp));
        ysh[n0 + 1] = xv.y * (norm * __expf(-d1 * d1 * inv_tp));
        ysh[n0 + 2] = xv.z * (norm * __expf(-d2 * d2 * inv_tp));
        ysh[n0 + 3] = xv.w * (norm * __expf(-d3 * d3 * inv_tp));
    }
    __syncthreads();

    const float f0v = f0[frame];
    const float df  = f0v * (1.0f / 16000.0f);   // fc increment per harmonic

    // preload this lane's 16 samples into registers (reused by all 16 k's)
    float yr[16];
    #pragma unroll
    for (int j = 0; j < 16; ++j) yr[j] = ysh[lane + 64 * j];

    // wave handles zero-based harmonic indices [16*wave, 16*wave+16)
    const int kbase = 16 * wave;
    #pragma unroll
    for (int b = 0; b < 4; ++b) {
        const int k0 = kbase + 4 * b;
        const float fc0 = df * (float)(k0 + 1);   // lowest fc in batch
        if (fc0 > 0.5f) {                         // whole batch above Nyquist
            if (lane < 4) tk[k0 + lane] = 0.0f;
            continue;
        }
        float cr[4], ci[4], Rc[4], Ri[4], re[4], im[4];
        #pragma unroll
        for (int u = 0; u < 4; ++u) {
            const float fc = df * (float)(k0 + u + 1);
            float t0 = fc * (float)lane;          // phase (revolutions) at n=lane
            t0 -= floorf(t0);
            cr[u] =  __builtin_amdgcn_cosf(t0);   // e^{-2pi i t0} = c - i s
            ci[u] = -__builtin_amdgcn_sinf(t0);
            float ts = fc * 64.0f;                // step rotator for n += 64
            ts -= floorf(ts);
            Rc[u] =  __builtin_amdgcn_cosf(ts);
            Ri[u] = -__builtin_amdgcn_sinf(ts);
            re[u] = 0.0f; im[u] = 0.0f;
        }
        #pragma unroll
        for (int j = 0; j < 16; ++j) {
            const float yv = yr[j];
            #pragma unroll
            for (int u = 0; u < 4; ++u) {
                re[u] = fmaf(yv, cr[u], re[u]);
                im[u] = fmaf(yv, ci[u], im[u]);
                const float nc = fmaf(cr[u], Rc[u], -(ci[u] * Ri[u]));
                const float ni = fmaf(cr[u], Ri[u],  (ci[u] * Rc[u]));
                cr[u] = nc; ci[u] = ni;
            }
        }
        #pragma unroll
        for (int u = 0; u < 4; ++u) {
            float r = re[u], i = im[u];
            #pragma unroll
            for (int off = 32; off > 0; off >>= 1) {
                r += __shfl_xor(r, off, 64);
                i += __shfl_xor(i, off, 64);
            }
            if (lane == 0) {
                const float fc = df * (float)(k0 + u + 1);
                tk[k0 + u] = (fc <= 0.5f) ? sqrtf(r * r + i * i) : 0.0f;
            }
        }
    }
    __syncthreads();

    // ---- normalize across k, write outputs (wave 0 only) ----
    if (tid < NH) {
        const float v = tk[tid];
        float s = v;
        #pragma unroll
        for (int off = 32; off > 0; off >>= 1)
            s += __shfl_xor(s, off, 64);
        hd[(size_t)frame * NH + tid] = v / s;
        if (tid == 0)
            amp[frame] = fminf(fmaxf(s * 2.0f, 0.0f), 1.0f);
    }
}

extern "C" void kernel_launch(void* const* d_in, const int* in_sizes, int n_in,
                              void* d_out, int out_size, void* d_ws, size_t ws_size,
                              hipStream_t stream) {
    const float* x   = (const float*)d_in[0];    // audio_frames [B,T,C,1024] f32
    const float* f0  = (const float*)d_in[1];    // f0 [B,T,C] f32
    const int F = in_sizes[1];                   // B*T*C frames (800)
    float* hd  = (float*)d_out;                  // [F,64]
    float* amp = (float*)d_out + (size_t)F * NH; // [F]
    morlet_kernel<<<F, 256, 0, stream>>>(x, f0, hd, amp);
}

// Round 3
// 62.544 us; speedup vs baseline: 1.2302x; 1.1213x over previous
//
#include <hip/hip_runtime.h>
#include <math.h>

#define WIN 1024
#define NH 64
#define FPB 4          // frames per block: one wave per frame
#define PAD 16         // LDS tail pad so distance-1 prefetch can overrun

// Goertzel formulation: one wave per frame, one lane per harmonic k=lane+1.
// s[n] = y[n] + 2cos(w) s[n-1] - s[n-2];  X = e^{-jw(M-1)} (s[M-1] - e^{-jw} s[M-2]).
// Window split into two 512-sample chains (A: n<512, B: n>=512, X = X_A + e^{-jw*512} X_B)
// for 2 independent fma chains per lane. y[n] broadcast from LDS (same-addr = free).
__global__ __launch_bounds__(256) void morlet_goertzel(
    const float* __restrict__ x,    // [F, 1024]
    const float* __restrict__ f0,   // [F]
    float* __restrict__ hd,         // [F, 64]
    float* __restrict__ amp,        // [F]
    int F)
{
    const int tid   = threadIdx.x;
    const int lane  = tid & 63;
    const int wave  = tid >> 6;
    const int frame = blockIdx.x * FPB + wave;
    const bool valid = frame < F;

    __shared__ float ysh[FPB][WIN + PAD];
    float* __restrict__ y = ysh[wave];

    float f0v = 0.0f;
    if (valid) {
        f0v = f0[frame];                       // issue early, overlaps staging
        const float4* xv = reinterpret_cast<const float4*>(x + (size_t)frame * WIN);
        const float inv_tp = 1.0f / 16000.0f;
        const float norm   = 0.0044603129f;    // 1/sqrt(pi*16000)
        #pragma unroll
        for (int j = 0; j < 4; ++j) {
            const int idx = lane + 64 * j;
            const float4 v = xv[idx];
            const int n0 = 4 * idx;
            const float d0 = (float)(n0 - 512);
            const float d1 = d0 + 1.0f;
            const float d2 = d0 + 2.0f;
            const float d3 = d0 + 3.0f;
            y[n0 + 0] = v.x * (norm * __expf(-d0 * d0 * inv_tp));
            y[n0 + 1] = v.y * (norm * __expf(-d1 * d1 * inv_tp));
            y[n0 + 2] = v.z * (norm * __expf(-d2 * d2 * inv_tp));
            y[n0 + 3] = v.w * (norm * __expf(-d3 * d3 * inv_tp));
        }
        if (lane < PAD) y[WIN + lane] = 0.0f;  // prefetch overrun area
    }
    __syncthreads();    // also orders LDS writes vs cross-lane reads
    if (!valid) return;

    const float fc = f0v * (float)(lane + 1) * (1.0f / 16000.0f); // revolutions/sample
    const float tw = fc - floorf(fc);
    const float c1 = __builtin_amdgcn_cosf(tw);   // cos(2*pi*fc)
    const float s1 = __builtin_amdgcn_sinf(tw);
    const float coef = 2.0f * c1;

    float a1 = 0.0f, a2 = 0.0f, b1 = 0.0f, b2 = 0.0f;

#define GSTEP(ch1, ch2, yv) { const float t_ = fmaf(coef, ch1, (yv) - ch2); ch2 = ch1; ch1 = t_; }

    // distance-1 prefetch (8 samples/chain per iter)
    float4 A0 = *(const float4*)&y[0];
    float4 A1 = *(const float4*)&y[4];
    float4 B0 = *(const float4*)&y[512];
    float4 B1 = *(const float4*)&y[516];

    #pragma unroll 2
    for (int i = 0; i < 512; i += 8) {
        const float4 nA0 = *(const float4*)&y[i + 8];
        const float4 nA1 = *(const float4*)&y[i + 12];
        const float4 nB0 = *(const float4*)&y[512 + i + 8];   // last iter reads pad
        const float4 nB1 = *(const float4*)&y[512 + i + 12];
        GSTEP(a1, a2, A0.x) GSTEP(a1, a2, A0.y) GSTEP(a1, a2, A0.z) GSTEP(a1, a2, A0.w)
        GSTEP(a1, a2, A1.x) GSTEP(a1, a2, A1.y) GSTEP(a1, a2, A1.z) GSTEP(a1, a2, A1.w)
        GSTEP(b1, b2, B0.x) GSTEP(b1, b2, B0.y) GSTEP(b1, b2, B0.z) GSTEP(b1, b2, B0.w)
        GSTEP(b1, b2, B1.x) GSTEP(b1, b2, B1.y) GSTEP(b1, b2, B1.z) GSTEP(b1, b2, B1.w)
        A0 = nA0; A1 = nA1; B0 = nB0; B1 = nB1;
    }
#undef GSTEP

    // epilogue: X_half = e^{-jw*511} * (s1 - e^{-jw} s2); phases in revolutions
    float tA = fc * 511.0f; tA -= floorf(tA);
    const float cA = __builtin_amdgcn_cosf(tA);
    const float sA = __builtin_amdgcn_sinf(tA);
    float t5 = fc * 512.0f; t5 -= floorf(t5);
    const float c5 = __builtin_amdgcn_cosf(t5);
    const float s5 = __builtin_amdgcn_sinf(t5);

    const float urA = fmaf(-c1, a2, a1);     // a1 - cos(w)*a2
    const float uiA = s1 * a2;               // +sin(w)*a2
    const float reA = fmaf(cA, urA,  sA * uiA);
    const float imA = fmaf(cA, uiA, -sA * urA);

    const float urB = fmaf(-c1, b2, b1);
    const float uiB = s1 * b2;
    const float reB1 = fmaf(cA, urB,  sA * uiB);
    const float imB1 = fmaf(cA, uiB, -sA * urB);
    const float reB  = fmaf(c5, reB1,  s5 * imB1);   // * e^{-jw*512}
    const float imB  = fmaf(c5, imB1, -s5 * reB1);

    const float re = reA + reB;
    const float im = imA + imB;
    const float v = (fc <= 0.5f) ? sqrtf(fmaf(re, re, im * im)) : 0.0f;

    float s = v;                              // sum over all 64 harmonics
    #pragma unroll
    for (int off = 32; off > 0; off >>= 1) s += __shfl_xor(s, off, 64);

    hd[(size_t)frame * NH + lane] = v / s;
    if (lane == 0) amp[frame] = fminf(fmaxf(s * 2.0f, 0.0f), 1.0f);
}

extern "C" void kernel_launch(void* const* d_in, const int* in_sizes, int n_in,
                              void* d_out, int out_size, void* d_ws, size_t ws_size,
                              hipStream_t stream) {
    const float* x   = (const float*)d_in[0];    // audio_frames [B,T,C,1024] f32
    const float* f0  = (const float*)d_in[1];    // f0 [B,T,C] f32
    const int F = in_sizes[1];                   // B*T*C frames (800)
    float* hd  = (float*)d_out;                  // [F,64]
    float* amp = (float*)d_out + (size_t)F * NH; // [F]
    const int blocks = (F + FPB - 1) / FPB;
    morlet_goertzel<<<blocks, 256, 0, stream>>>(x, f0, hd, amp, F);
}

// Round 4
// 60.040 us; speedup vs baseline: 1.2815x; 1.0417x over previous
//
#include <hip/hip_runtime.h>
#include <math.h>

#define WIN 1024
#define NH 64
#define PAD 16         // LDS tail pad so distance-1 prefetch can overrun

// Goertzel, one block (4 waves) per frame, one lane per harmonic k=lane+1.
// Frame split into 8 chunks of 128 samples; wave w owns chunks 2w, 2w+1 as two
// independent fma chains (ILP). Partial DTFTs combined exactly:
//   X = sum_q e^{-jw*128q} * [e^{-jw*127} (s1 - e^{-jw} s2)]_q
// (phase folded into one rotation per chunk). Cross-wave combine via LDS.
__global__ __launch_bounds__(256) void morlet_goertzel(
    const float* __restrict__ x,    // [F, 1024]
    const float* __restrict__ f0,   // [F]
    float* __restrict__ hd,         // [F, 64]
    float* __restrict__ amp)        // [F]
{
    const int frame = blockIdx.x;
    const int tid   = threadIdx.x;
    const int lane  = tid & 63;
    const int wave  = tid >> 6;

    __shared__ float y[WIN + PAD];
    __shared__ float pr[4][NH];
    __shared__ float pi_[4][NH];

    const float f0v = f0[frame];

    // ---- stage windowed frame into LDS (float4 per thread) ----
    {
        const float4 v =
            reinterpret_cast<const float4*>(x + (size_t)frame * WIN)[tid];
        const float inv_tp = 1.0f / 16000.0f;
        const float norm   = 0.0044603129f;    // 1/sqrt(pi*16000)
        const int n0 = 4 * tid;
        const float d0 = (float)(n0 - 512);
        const float d1 = d0 + 1.0f;
        const float d2 = d0 + 2.0f;
        const float d3 = d0 + 3.0f;
        y[n0 + 0] = v.x * (norm * __expf(-d0 * d0 * inv_tp));
        y[n0 + 1] = v.y * (norm * __expf(-d1 * d1 * inv_tp));
        y[n0 + 2] = v.z * (norm * __expf(-d2 * d2 * inv_tp));
        y[n0 + 3] = v.w * (norm * __expf(-d3 * d3 * inv_tp));
        if (tid < PAD) y[WIN + tid] = 0.0f;    // prefetch overrun area
    }
    __syncthreads();

    const float fc = f0v * (float)(lane + 1) * (1.0f / 16000.0f); // rev/sample
    const float tw = fc - floorf(fc);
    const float c1  = __builtin_amdgcn_cosf(tw);  // cos(2*pi*fc)
    const float sn1 = __builtin_amdgcn_sinf(tw);  // sin(2*pi*fc)
    const float coef = 2.0f * c1;

    float a1 = 0.0f, a2 = 0.0f, b1 = 0.0f, b2 = 0.0f;

#define GSTEP(ch1, ch2, yv) { const float t_ = fmaf(coef, ch1, (yv) - ch2); ch2 = ch1; ch1 = t_; }

    const int base = 256 * wave;               // chain A: [base, base+128)
    // distance-1 prefetch                      // chain B: [base+128, base+256)
    float4 A0 = *(const float4*)&y[base];
    float4 A1 = *(const float4*)&y[base + 4];
    float4 B0 = *(const float4*)&y[base + 128];
    float4 B1 = *(const float4*)&y[base + 132];

    #pragma unroll 4
    for (int i = 0; i < 128; i += 8) {
        const float4 nA0 = *(const float4*)&y[base + i + 8];
        const float4 nA1 = *(const float4*)&y[base + i + 12];
        const float4 nB0 = *(const float4*)&y[base + 128 + i + 8];  // last iter hits pad
        const float4 nB1 = *(const float4*)&y[base + 128 + i + 12];
        GSTEP(a1, a2, A0.x) GSTEP(a1, a2, A0.y) GSTEP(a1, a2, A0.z) GSTEP(a1, a2, A0.w)
        GSTEP(a1, a2, A1.x) GSTEP(a1, a2, A1.y) GSTEP(a1, a2, A1.z) GSTEP(a1, a2, A1.w)
        GSTEP(b1, b2, B0.x) GSTEP(b1, b2, B0.y) GSTEP(b1, b2, B0.z) GSTEP(b1, b2, B0.w)
        GSTEP(b1, b2, B1.x) GSTEP(b1, b2, B1.y) GSTEP(b1, b2, B1.z) GSTEP(b1, b2, B1.w)
        A0 = nA0; A1 = nA1; B0 = nB0; B1 = nB1;
    }
#undef GSTEP

    // chunk q partial: e^{-jw(128q+127)} * ((s1 - c1*s2) + j*sn1*s2)
    const int qA = 2 * wave, qB = 2 * wave + 1;
    float tA = fc * (float)(128 * qA + 127); tA -= floorf(tA);
    float tB = fc * (float)(128 * qB + 127); tB -= floorf(tB);
    const float cA = __builtin_amdgcn_cosf(tA), sA = __builtin_amdgcn_sinf(tA);
    const float cB = __builtin_amdgcn_cosf(tB), sB = __builtin_amdgcn_sinf(tB);

    const float urA = fmaf(-c1, a2, a1);
    const float uiA = sn1 * a2;
    const float urB = fmaf(-c1, b2, b1);
    const float uiB = sn1 * b2;

    const float reW = fmaf(cA, urA,  sA * uiA) + fmaf(cB, urB,  sB * uiB);
    const float imW = fmaf(cA, uiA, -sA * urA) + fmaf(cB, uiB, -sB * urB);

    pr[wave][lane]  = reW;
    pi_[wave][lane] = imW;
    __syncthreads();

    // ---- wave 0: combine 4 wave-partials, magnitude, normalize, write ----
    if (tid < NH) {
        const float re = pr[0][tid] + pr[1][tid] + pr[2][tid] + pr[3][tid];
        const float im = pi_[0][tid] + pi_[1][tid] + pi_[2][tid] + pi_[3][tid];
        const float fck = f0v * (float)(tid + 1) * (1.0f / 16000.0f);
        const float v = (fck <= 0.5f) ? sqrtf(fmaf(re, re, im * im)) : 0.0f;
        float s = v;
        #pragma unroll
        for (int off = 32; off > 0; off >>= 1) s += __shfl_xor(s, off, 64);
        hd[(size_t)frame * NH + tid] = v / s;
        if (tid == 0) amp[frame] = fminf(fmaxf(s * 2.0f, 0.0f), 1.0f);
    }
}

extern "C" void kernel_launch(void* const* d_in, const int* in_sizes, int n_in,
                              void* d_out, int out_size, void* d_ws, size_t ws_size,
                              hipStream_t stream) {
    const float* x   = (const float*)d_in[0];    // audio_frames [B,T,C,1024] f32
    const float* f0  = (const float*)d_in[1];    // f0 [B,T,C] f32
    const int F = in_sizes[1];                   // B*T*C frames (800)
    float* hd  = (float*)d_out;                  // [F,64]
    float* amp = (float*)d_out + (size_t)F * NH; // [F]
    morlet_goertzel<<<F, 256, 0, stream>>>(x, f0, hd, amp);
}